// Round 12
// baseline (293.930 us; speedup 1.0000x reference)
//
#include <hip/hip_runtime.h>

#define CH 16
#define NB 8

typedef unsigned short u16;
typedef unsigned int u32;
typedef __attribute__((ext_vector_type(8))) short s16x8;
typedef __attribute__((ext_vector_type(4))) float f32x4;

__device__ __forceinline__ float bflo(u32 u) { return __uint_as_float(u << 16); }
__device__ __forceinline__ float bfhi(u32 u) { return __uint_as_float(u & 0xffff0000u); }
__device__ __forceinline__ u32 bfrnd(float f) {
  u32 u = __float_as_uint(f);
  return (u + 0x7fffu + ((u >> 16) & 1u)) >> 16;
}
__device__ __forceinline__ u32 packbf(float lo, float hi) {
  return bfrnd(lo) | (bfrnd(hi) << 16);
}

// ---- Stem via MFMA implicit GEMM (validated R10 form) ---------------------
__global__ __launch_bounds__(256) void stem_mfma(
    const float* __restrict__ x, const int* __restrict__ mask,
    const float* __restrict__ wst, u16* __restrict__ yout,
    float* __restrict__ pool_sum, float* __restrict__ cnt)
{
  __shared__ u16 tile[12 * 12 * 12];
  __shared__ u16 lb[4 * 512];
  __shared__ u32 toff[128];
  __shared__ float lC[4 * 16 * 17];
  __shared__ float lmsk[64];

  const int b = blockIdx.y;
  const int tb = blockIdx.x;
  const int z0 = (tb >> 6) * 8;
  const int y0 = ((tb >> 3) & 7) * 8;
  const int x0 = (tb & 7) * 8;
  const int tid = threadIdx.x;

  if (tb == 0) {
    if (tid < 96) pool_sum[b * 96 + tid] = 0.f;
    else if (tid < 102) cnt[b * 6 + (tid - 96)] = 0.f;
  }

  if (tid < 128) {
    const int k = min(tid, 124);
    toff[tid] = (u32)((k / 25) * 144 + ((k / 5) % 5) * 12 + (k % 5));
  }
  for (int e = tid; e < 2048; e += 256) {
    const int i = e >> 9;
    const int r = e & 511;
    const int l = r >> 3, j = r & 7;
    const int k = i * 32 + (l >> 4) * 8 + j;
    const int n = l & 15;
    const float val = (k < 125) ? wst[k * 16 + n] : 0.f;
    lb[i * 512 + l * 8 + j] = (u16)bfrnd(val);
  }
  for (int i = tid; i < 1728; i += 256) {
    const int lz = i / 144;
    const int lyr = (i / 12) % 12;
    const int lxr = i % 12;
    const int gz = z0 + lz - 2, gy = y0 + lyr - 2, gx = x0 + lxr - 2;
    float v = 0.f;
    if ((unsigned)gz < 64u && (unsigned)gy < 64u && (unsigned)gx < 64u) {
      const int gi = ((b * 64 + gz) * 64 + gy) * 64 + gx;
      v = x[gi] * (float)mask[gi];
    }
    tile[i] = (u16)bfrnd(v);
  }
  __syncthreads();

  const int wv = tid >> 6;
  const int lane = tid & 63;
  const int m = lane & 15;
  const int quad = lane >> 4;
  const int vy = m >> 2, vx = m & 3;

  u32 tof[4][8];
#pragma unroll
  for (int i = 0; i < 4; ++i)
#pragma unroll
    for (int j = 0; j < 8; ++j) tof[i][j] = toff[i * 32 + quad * 8 + j];
  const s16x8* lbv = (const s16x8*)lb;
  s16x8 bfr[4];
#pragma unroll
  for (int i = 0; i < 4; ++i) bfr[i] = lbv[i * 64 + lane];

  for (int s = 0; s < 8; ++s) {
    const int sz = (s >> 2) * 4, sy = ((s >> 1) & 1) * 4, sx = (s & 1) * 4;

    if (tid < 64) {
      const int oz2 = z0 + sz + (tid >> 4);
      const int oy2 = y0 + sy + ((tid >> 2) & 3);
      const int ox2 = x0 + sx + (tid & 3);
      lmsk[tid] = (float)mask[((b * 64 + oz2) * 64 + oy2) * 64 + ox2];
    }

    const int vbase = (sz + wv) * 144 + (sy + vy) * 12 + (sx + vx);
    f32x4 acc = {0.f, 0.f, 0.f, 0.f};
#pragma unroll
    for (int i = 0; i < 4; ++i) {
      s16x8 af;
#pragma unroll
      for (int j = 0; j < 8; ++j)
        af[j] = (short)tile[vbase + tof[i][j]];
      acc = __builtin_amdgcn_mfma_f32_16x16x32_bf16(af, bfr[i], acc, 0, 0, 0);
    }
    __syncthreads();

    {
      float* lCw = lC + wv * 272;
      const int n = lane & 15;
#pragma unroll
      for (int reg = 0; reg < 4; ++reg) {
        const int row = quad * 4 + reg;
        lCw[row * 17 + n] = fmaxf(acc[reg], 0.f) * lmsk[wv * 16 + row];
      }
    }
    __syncthreads();

    {
      const int vox_l = tid >> 2;
      const int cg = (tid & 3) * 4;
      const float* src = lC + (vox_l >> 4) * 272 + (vox_l & 15) * 17 + cg;
      const float f0 = src[0], f1 = src[1], f2 = src[2], f3 = src[3];
      const int Z = z0 + sz + (vox_l >> 4);
      const int Y = y0 + sy + ((vox_l >> 2) & 3);
      const int X = x0 + sx + (vox_l & 3);
      const int gi = ((b * 64 + Z) * 64 + Y) * 64 + X;
      uint2* op = (uint2*)(yout + (size_t)gi * CH + cg);
      op[0] = make_uint2(packbf(f0, f1), packbf(f2, f3));
    }
  }
}

// ---- Stages 0..2: MFMA implicit GEMM with LDS-staged input halo -----------
// Block = 4x4x4 output tile (wave = z-slice). Input 9^3 x 16ch bf16 halo
// staged coalesced + zero-filled -> A-gather is unmasked ds_read_b128.
// Taps >= 27 have B == 0, so their A values are don't-care.
__global__ __launch_bounds__(256) void stage_mfma(
    const u16* __restrict__ yin, const float* __restrict__ w,
    const int* __restrict__ m_in_i, const float* __restrict__ m_in_f,
    u16* __restrict__ yout, float* __restrict__ m_out,
    float* __restrict__ pool_sum, float* __restrict__ cnt,
    const int S, const int stage)
{
  __shared__ u16 tile[9 * 9 * 9 * 16];   // 23.3 KB
  __shared__ u16 lb[14 * 512];           // 14 KB
  __shared__ u32 tapoff[28];
  __shared__ float lC[4 * 16 * 17];
  __shared__ float lmp[64];

  const int So = S >> 1;
  const int nt = So >> 2;                // tiles per axis
  const int b = blockIdx.y;
  const int tid = threadIdx.x;
  const int tb = blockIdx.x;
  const int otz = tb / (nt * nt);
  const int oty = (tb / nt) % nt;
  const int otx = tb % nt;
  const int oz0 = otz * 4, oy0 = oty * 4, ox0 = otx * 4;
  const int iz0 = 2 * oz0 - 1, iy0 = 2 * oy0 - 1, ix0 = 2 * ox0 - 1;

  // tap -> LDS offset LUT (u16 units)
  if (tid < 28) {
    const int k = min((int)tid, 26);
    tapoff[tid] = (u32)((((k / 9) * 9 + (k / 3) % 3) * 9 + (k % 3)) * 16);
  }

  // B fragments
  for (int e = tid; e < 14 * 512; e += 256) {
    const int i = e >> 9;
    const int r = e & 511;
    const int l = r >> 3;
    const int j = r & 7;
    const int tap = 2 * i + (l >> 5);
    const int cin = ((l >> 4) & 1) * 8 + j;
    const int n = l & 15;
    const float val = (tap < 27) ? w[(tap * 16 + cin) * 16 + n] : 0.f;
    lb[i * 512 + l * 8 + j] = (u16)bfrnd(val);
  }

  // stage input halo: 81 rows x 9 voxels x 16ch = 1458 x 16B, coalesced
  for (int e = tid; e < 1458; e += 256) {
    const int row = e / 18;              // lz*9+ly
    const int c = e % 18;
    const int lz = row / 9, ly = row % 9;
    const int lx = c >> 1, half = c & 1;
    const int gz = iz0 + lz, gy = iy0 + ly, gx = ix0 + lx;
    uint4 v = make_uint4(0u, 0u, 0u, 0u);
    if ((unsigned)gz < (unsigned)S && (unsigned)gy < (unsigned)S &&
        (unsigned)gx < (unsigned)S) {
      v = *(const uint4*)(yin +
                          (size_t)(((b * S + gz) * S + gy) * S + gx) * 16 +
                          half * 8);
    }
    *(uint4*)(tile + (size_t)e * 8) = v;   // ((lz*9+ly)*9+lx)*16 + half*8
  }

  // pooled mask per output voxel (first 64 threads)
  if (tid < 64) {
    const int oz = oz0 + (tid >> 4);
    const int oy = oy0 + ((tid >> 2) & 3);
    const int ox = ox0 + (tid & 3);
    float mp = 0.f;
#pragma unroll
    for (int dz = 0; dz < 2; ++dz)
#pragma unroll
      for (int dy = 0; dy < 2; ++dy)
#pragma unroll
        for (int dx = 0; dx < 2; ++dx) {
          const int mi =
              ((b * S + 2 * oz + dz) * S + 2 * oy + dy) * S + 2 * ox + dx;
          const float mv = m_in_i ? (float)m_in_i[mi] : m_in_f[mi];
          mp = fmaxf(mp, mv);
        }
    lmp[tid] = mp;
  }
  __syncthreads();

  const int wv = tid >> 6;               // z-slice of the 4x4x4 tile
  const int lane = tid & 63;
  const int m = lane & 15;               // y*4+x
  const int quad = lane >> 4;
  const int qh = quad >> 1;
  const int qlo = quad & 1;
  const int my = m >> 2, mx = m & 3;

  // per-lane gather base (u16 units) + hoisted tap offsets
  const int vb = (((2 * wv) * 9 + 2 * my) * 9 + 2 * mx) * 16 + qlo * 8;
  u32 goff[14];
#pragma unroll
  for (int i = 0; i < 14; ++i) goff[i] = (u32)vb + tapoff[2 * i + qh];

  const s16x8* lbv = (const s16x8*)lb;
  f32x4 acc = {0.f, 0.f, 0.f, 0.f};
#pragma unroll
  for (int i = 0; i < 14; ++i) {
    const s16x8 afrag = *(const s16x8*)(tile + goff[i]);
    const s16x8 bfrag = lbv[i * 64 + lane];
    acc = __builtin_amdgcn_mfma_f32_16x16x32_bf16(afrag, bfrag, acc, 0, 0, 0);
  }

  {
    float* lCw = lC + wv * 272;
    const int n = lane & 15;
#pragma unroll
    for (int reg = 0; reg < 4; ++reg) {
      const int row = quad * 4 + reg;
      lCw[row * 17 + n] = fmaxf(acc[reg], 0.f) * lmp[wv * 16 + row];
    }
  }
  __syncthreads();

  {
    const int vox_l = tid >> 2;          // z*16 + y*4 + x
    const int cg = (tid & 3) * 4;
    const float* src = lC + (vox_l >> 4) * 272 + (vox_l & 15) * 17 + cg;
    const float f0 = src[0], f1 = src[1], f2 = src[2], f3 = src[3];
    const int Z = oz0 + (vox_l >> 4);
    const int Y = oy0 + ((vox_l >> 2) & 3);
    const int X = ox0 + (vox_l & 3);
    const size_t gi = (size_t)b * (So * So * So) + ((size_t)Z * So + Y) * So + X;
    uint2* op = (uint2*)(yout + gi * 16 + cg);
    op[0] = make_uint2(packbf(f0, f1), packbf(f2, f3));
    if ((tid & 3) == 0) m_out[gi] = lmp[vox_l];
  }

  if (tid < 16) {
    float s = 0.f;
#pragma unroll 16
    for (int v = 0; v < 64; ++v)
      s += lC[(v >> 4) * 272 + (v & 15) * 17 + tid];
    atomicAdd(&pool_sum[(b * 6 + stage) * 16 + tid], s);
  } else if (tid == 16) {
    float c = 0.f;
#pragma unroll 16
    for (int v = 0; v < 64; ++v) c += lmp[v];
    atomicAdd(&cnt[b * 6 + stage], c);
  }
}

// --------- Tail: stages 3,4,5 entirely in LDS + pools + full head MLP ------
__global__ __launch_bounds__(256) void tail_kernel(
    const u16* __restrict__ y3g, const float* __restrict__ m3g,
    const float* __restrict__ wstg,
    const float* __restrict__ meta, const float* __restrict__ sched,
    const float* __restrict__ mw1, const float* __restrict__ mb1,
    const float* __restrict__ mw2, const float* __restrict__ mb2,
    const float* __restrict__ matw, const float* __restrict__ matb,
    const float* __restrict__ schw, const float* __restrict__ schb,
    const float* __restrict__ f1w, const float* __restrict__ f1b,
    const float* __restrict__ f2w, const float* __restrict__ f2b,
    const float* __restrict__ pool_sum, const float* __restrict__ cnt,
    float* __restrict__ out)
{
  const int b = blockIdx.x;
  const int t = threadIdx.x;
  __shared__ float ly3[8 * 8 * 8 * 16];
  __shared__ float lm3[512];
  __shared__ float ly4[4 * 4 * 4 * 16];
  __shared__ float lm4[64];
  __shared__ float ly5[8 * 16];
  __shared__ float lm5[8];
  __shared__ float lsum[3][16];
  __shared__ float lcnt[3];
  __shared__ float invec[112];
  __shared__ float hbuf[32];
  __shared__ float zbuf[256];
  __shared__ float part[2];

  const uint4* yb = (const uint4*)(y3g + (size_t)b * 8192);
  for (int i = t; i < 1024; i += 256) {
    const uint4 p = yb[i];
    float* d = &ly3[i * 8];
    d[0] = bflo(p.x); d[1] = bfhi(p.x);
    d[2] = bflo(p.y); d[3] = bfhi(p.y);
    d[4] = bflo(p.z); d[5] = bfhi(p.z);
    d[6] = bflo(p.w); d[7] = bfhi(p.w);
  }
  for (int i = t; i < 512; i += 256) lm3[i] = m3g[b * 512 + i];
  __syncthreads();

  // ---- stage 3: 8^3 -> 4^3, thread = (vox, co-group of 4)
  {
    const float* w = wstg + 3 * 27 * 256;
    const int vox = t >> 2, cog = (t & 3) * 4;
    const int oz = vox >> 4, oy = (vox >> 2) & 3, ox = vox & 3;
    float acc[4] = {0.f, 0.f, 0.f, 0.f};
#pragma unroll
    for (int dz = 0; dz < 3; ++dz)
#pragma unroll
      for (int dy = 0; dy < 3; ++dy)
#pragma unroll
        for (int dx = 0; dx < 3; ++dx) {
          const int iz = 2 * oz + dz - 1, iy = 2 * oy + dy - 1,
                    ix = 2 * ox + dx - 1;
          const float s = ((unsigned)iz < 8u && (unsigned)iy < 8u &&
                           (unsigned)ix < 8u) ? 1.f : 0.f;
          const int idx = ((min(max(iz, 0), 7) * 8 + min(max(iy, 0), 7)) * 8 +
                           min(max(ix, 0), 7)) * 16;
          const float* wp = w + ((dz * 3 + dy) * 3 + dx) * 256;
#pragma unroll
          for (int ci = 0; ci < 16; ++ci) {
            const float v = ly3[idx + ci] * s;
#pragma unroll
            for (int c = 0; c < 4; ++c)
              acc[c] = fmaf(v, wp[ci * 16 + cog + c], acc[c]);
          }
        }
    float mp = 0.f;
#pragma unroll
    for (int dz = 0; dz < 2; ++dz)
#pragma unroll
      for (int dy = 0; dy < 2; ++dy)
#pragma unroll
        for (int dx = 0; dx < 2; ++dx)
          mp = fmaxf(mp, lm3[((2 * oz + dz) * 8 + 2 * oy + dy) * 8 +
                             2 * ox + dx]);
#pragma unroll
    for (int c = 0; c < 4; ++c)
      ly4[vox * 16 + cog + c] = fmaxf(acc[c], 0.f) * mp;
    if (cog == 0) lm4[vox] = mp;
  }
  __syncthreads();

  // ---- stage-3 sums and stage 4: 4^3 -> 2^3
  if (t < 16) {
    float s = 0.f;
#pragma unroll 16
    for (int v = 0; v < 64; ++v) s += ly4[v * 16 + t];
    lsum[0][t] = s;
  } else if (t == 16) {
    float s = 0.f;
#pragma unroll 16
    for (int v = 0; v < 64; ++v) s += lm4[v];
    lcnt[0] = s;
  }
  float s4val = 0.f, s4mp = 0.f;
  const int vox4 = (t >> 4) & 7, co4 = t & 15;
  if (t < 128) {
    const float* w = wstg + 4 * 27 * 256;
    const int oz = vox4 >> 2, oy = (vox4 >> 1) & 1, ox = vox4 & 1;
    float acc = 0.f;
#pragma unroll
    for (int dz = 0; dz < 3; ++dz)
#pragma unroll
      for (int dy = 0; dy < 3; ++dy)
#pragma unroll
        for (int dx = 0; dx < 3; ++dx) {
          const int iz = 2 * oz + dz - 1, iy = 2 * oy + dy - 1,
                    ix = 2 * ox + dx - 1;
          const float s = ((unsigned)iz < 4u && (unsigned)iy < 4u &&
                           (unsigned)ix < 4u) ? 1.f : 0.f;
          const int idx = ((min(max(iz, 0), 3) * 4 + min(max(iy, 0), 3)) * 4 +
                           min(max(ix, 0), 3)) * 16;
          const float* wp = w + ((dz * 3 + dy) * 3 + dx) * 256 + co4;
#pragma unroll
          for (int ci = 0; ci < 16; ++ci)
            acc = fmaf(ly4[idx + ci] * s, wp[ci * 16], acc);
        }
    float mp = 0.f;
#pragma unroll
    for (int dz = 0; dz < 2; ++dz)
#pragma unroll
      for (int dy = 0; dy < 2; ++dy)
#pragma unroll
        for (int dx = 0; dx < 2; ++dx)
          mp = fmaxf(mp, lm4[((2 * (vox4 >> 2) + dz) * 4 +
                              2 * ((vox4 >> 1) & 1) + dy) * 4 +
                             2 * (vox4 & 1) + dx]);
    s4val = fmaxf(acc, 0.f) * mp;
    s4mp = mp;
  }
  __syncthreads();
  if (t < 128) {
    ly5[vox4 * 16 + co4] = s4val;
    if (co4 == 0) lm5[vox4] = s4mp;
  }
  __syncthreads();

  // ---- stage-4 sums and stage 5: 2^3 -> 1
  if (t < 16) {
    float s = 0.f;
#pragma unroll
    for (int v = 0; v < 8; ++v) s += ly5[v * 16 + t];
    lsum[1][t] = s;
  } else if (t == 16) {
    lcnt[1] = lm5[0] + lm5[1] + lm5[2] + lm5[3] + lm5[4] + lm5[5] + lm5[6] +
              lm5[7];
  }
  if (t >= 64 && t < 80) {
    const int co = t - 64;
    const float* w = wstg + 5 * 27 * 256;
    float acc = 0.f;
#pragma unroll
    for (int dz = 0; dz < 3; ++dz)
#pragma unroll
      for (int dy = 0; dy < 3; ++dy)
#pragma unroll
        for (int dx = 0; dx < 3; ++dx) {
          const int iz = dz - 1, iy = dy - 1, ix = dx - 1;
          const float s = ((unsigned)iz < 2u && (unsigned)iy < 2u &&
                           (unsigned)ix < 2u) ? 1.f : 0.f;
          const int idx = ((min(max(iz, 0), 1) * 2 + min(max(iy, 0), 1)) * 2 +
                           min(max(ix, 0), 1)) * 16;
          const float* wp = w + ((dz * 3 + dy) * 3 + dx) * 256 + co;
#pragma unroll
          for (int ci = 0; ci < 16; ++ci)
            acc = fmaf(ly5[idx + ci] * s, wp[ci * 16], acc);
        }
    float mp = 0.f;
#pragma unroll
    for (int v = 0; v < 8; ++v) mp = fmaxf(mp, lm5[v]);
    lsum[2][co] = fmaxf(acc, 0.f) * mp;
    if (co == 0) lcnt[2] = mp;
  }
  __syncthreads();

  // ---- build invec; meta layer 1
  if (t < 48) {
    const int s = t >> 4;
    invec[t] = pool_sum[b * 96 + t] / fmaxf(cnt[b * 6 + s], 1.f);
  } else if (t < 96) {
    const int s = (t >> 4) - 3;
    invec[t] = lsum[s][t & 15] / fmaxf(lcnt[s], 1.f);
  } else if (t < 128) {
    const int j = t - 96;
    float h = mb1[j];
#pragma unroll
    for (int k = 0; k < 3; ++k) h = fmaf(meta[b * 3 + k], mw1[k * 32 + j], h);
    hbuf[j] = fmaxf(h, 0.f);
  }
  __syncthreads();
  if (t < 16) {
    float e = mb2[t];
#pragma unroll
    for (int j = 0; j < 32; ++j) e = fmaf(hbuf[j], mw2[j * 16 + t], e);
    invec[96 + t] = e;  // no ReLU on meta_emb
  }
  __syncthreads();
  if (t < 128) {
    float a = matb[t];
#pragma unroll 16
    for (int k = 0; k < 112; ++k) a = fmaf(invec[k], matw[k * 128 + t], a);
    zbuf[t] = fmaxf(a, 0.f);
    float s = schb[t];
#pragma unroll 16
    for (int k = 0; k < 128; ++k)
      s = fmaf(sched[b * 128 + k], schw[k * 128 + t], s);
    zbuf[128 + t] = fmaxf(s, 0.f);
  }
  __syncthreads();
  if (t < 128) {
    float a = f1b[t];
#pragma unroll 16
    for (int k = 0; k < 256; ++k) a = fmaf(zbuf[k], f1w[k * 128 + t], a);
    float v = fmaxf(a, 0.f) * f2w[t];
#pragma unroll
    for (int off = 32; off > 0; off >>= 1) v += __shfl_xor(v, off, 64);
    if ((t & 63) == 0) part[t >> 6] = v;
  }
  __syncthreads();
  if (t == 0) out[b] = part[0] + part[1] + f2b[0];
}

extern "C" void kernel_launch(void* const* d_in, const int* in_sizes, int n_in,
                              void* d_out, int out_size, void* d_ws,
                              size_t ws_size, hipStream_t stream)
{
  (void)in_sizes; (void)n_in; (void)out_size; (void)ws_size;
  const float* x      = (const float*)d_in[0];
  const int*   mask   = (const int*)  d_in[1];
  const float* meta   = (const float*)d_in[2];
  const float* sched  = (const float*)d_in[3];
  const float* w_stem = (const float*)d_in[4];
  const float* w_stg  = (const float*)d_in[5];
  const float* mw1    = (const float*)d_in[6];
  const float* mb1    = (const float*)d_in[7];
  const float* mw2    = (const float*)d_in[8];
  const float* mb2    = (const float*)d_in[9];
  const float* matw   = (const float*)d_in[10];
  const float* matb   = (const float*)d_in[11];
  const float* schw   = (const float*)d_in[12];
  const float* schb   = (const float*)d_in[13];
  const float* f1w    = (const float*)d_in[14];
  const float* f1b    = (const float*)d_in[15];
  const float* f2w    = (const float*)d_in[16];
  const float* f2b    = (const float*)d_in[17];
  float* out = (float*)d_out;

  char* ws = (char*)d_ws;
  size_t off = 0;
  auto alloc = [&](size_t nbytes) -> void* {
    void* p = ws + off;
    off += (nbytes + 255) & ~(size_t)255;
    return p;
  };

  u16* y0 = (u16*)alloc((size_t)NB * 64 * 64 * 64 * CH * 2);
  u16* y1 = (u16*)alloc((size_t)NB * 32 * 32 * 32 * CH * 2);
  u16* y2 = (u16*)alloc((size_t)NB * 16 * 16 * 16 * CH * 2);
  u16* y3 = (u16*)alloc((size_t)NB * 8 * 8 * 8 * CH * 2);
  float* m1 = (float*)alloc((size_t)NB * 32 * 32 * 32 * 4);
  float* m2 = (float*)alloc((size_t)NB * 16 * 16 * 16 * 4);
  float* m3 = (float*)alloc((size_t)NB * 8 * 8 * 8 * 4);
  float* pool_sum = (float*)alloc((NB * 96 + NB * 6) * 4);
  float* cnt = pool_sum + NB * 96;

  stem_mfma<<<dim3(512, NB), 256, 0, stream>>>(x, mask, w_stem, y0,
                                               pool_sum, cnt);

  // stage 0: 64->32, (32/4)^3 = 512 tiles/batch
  stage_mfma<<<dim3(512, NB), 256, 0, stream>>>(
      y0, w_stg + 0 * 27 * 256, mask, (const float*)nullptr, y1, m1,
      pool_sum, cnt, 64, 0);
  // stage 1: 32->16, 64 tiles/batch
  stage_mfma<<<dim3(64, NB), 256, 0, stream>>>(
      y1, w_stg + 1 * 27 * 256, (const int*)nullptr, m1, y2, m2,
      pool_sum, cnt, 32, 1);
  // stage 2: 16->8, 8 tiles/batch
  stage_mfma<<<dim3(8, NB), 256, 0, stream>>>(
      y2, w_stg + 2 * 27 * 256, (const int*)nullptr, m2, y3, m3,
      pool_sum, cnt, 16, 2);

  tail_kernel<<<NB, 256, 0, stream>>>(y3, m3, w_stg, meta, sched,
                                      mw1, mb1, mw2, mb2, matw, matb,
                                      schw, schb, f1w, f1b, f2w, f2b,
                                      pool_sum, cnt, out);
}

// Round 13
// 243.788 us; speedup vs baseline: 1.2057x; 1.2057x over previous
//
#include <hip/hip_runtime.h>

#define CH 16
#define NB 8

typedef unsigned short u16;
typedef unsigned int u32;
typedef __attribute__((ext_vector_type(8))) short s16x8;
typedef __attribute__((ext_vector_type(4))) float f32x4;

__device__ __forceinline__ float bflo(u32 u) { return __uint_as_float(u << 16); }
__device__ __forceinline__ float bfhi(u32 u) { return __uint_as_float(u & 0xffff0000u); }
__device__ __forceinline__ u32 bfrnd(float f) {
  u32 u = __float_as_uint(f);
  return (u + 0x7fffu + ((u >> 16) & 1u)) >> 16;
}
__device__ __forceinline__ u32 packbf(float lo, float hi) {
  return bfrnd(lo) | (bfrnd(hi) << 16);
}

// ---- Prep: build bf16 B-fragments for all 3 MFMA stages (once) ------------
__global__ __launch_bounds__(256) void bprep_kernel(
    const float* __restrict__ w_stg, u16* __restrict__ bpre)
{
  const int e = blockIdx.x * 256 + (int)threadIdx.x;
  if (e >= 3 * 7168) return;
  const int s = e / 7168, r0 = e % 7168;
  const int i = r0 >> 9;
  const int r = r0 & 511;
  const int l = r >> 3, j = r & 7;
  const int tap = 2 * i + (l >> 5);
  const int cin = ((l >> 4) & 1) * 8 + j;
  const int n = l & 15;
  const float* w = w_stg + s * 27 * 256;
  const float val = (tap < 27) ? w[(tap * 16 + cin) * 16 + n] : 0.f;
  bpre[s * 7168 + i * 512 + l * 8 + j] = (u16)bfrnd(val);
}

// ---- Stem via MFMA implicit GEMM (validated R10 form) ---------------------
__global__ __launch_bounds__(256) void stem_mfma(
    const float* __restrict__ x, const int* __restrict__ mask,
    const float* __restrict__ wst, u16* __restrict__ yout,
    float* __restrict__ pool_sum, float* __restrict__ cnt)
{
  __shared__ u16 tile[12 * 12 * 12];
  __shared__ u16 lb[4 * 512];
  __shared__ u32 toff[128];
  __shared__ float lC[4 * 16 * 17];
  __shared__ float lmsk[64];

  const int b = blockIdx.y;
  const int tb = blockIdx.x;
  const int z0 = (tb >> 6) * 8;
  const int y0 = ((tb >> 3) & 7) * 8;
  const int x0 = (tb & 7) * 8;
  const int tid = threadIdx.x;

  if (tb == 0) {
    if (tid < 96) pool_sum[b * 96 + tid] = 0.f;
    else if (tid < 102) cnt[b * 6 + (tid - 96)] = 0.f;
  }

  if (tid < 128) {
    const int k = min(tid, 124);
    toff[tid] = (u32)((k / 25) * 144 + ((k / 5) % 5) * 12 + (k % 5));
  }
  for (int e = tid; e < 2048; e += 256) {
    const int i = e >> 9;
    const int r = e & 511;
    const int l = r >> 3, j = r & 7;
    const int k = i * 32 + (l >> 4) * 8 + j;
    const int n = l & 15;
    const float val = (k < 125) ? wst[k * 16 + n] : 0.f;
    lb[i * 512 + l * 8 + j] = (u16)bfrnd(val);
  }
  for (int i = tid; i < 1728; i += 256) {
    const int lz = i / 144;
    const int lyr = (i / 12) % 12;
    const int lxr = i % 12;
    const int gz = z0 + lz - 2, gy = y0 + lyr - 2, gx = x0 + lxr - 2;
    float v = 0.f;
    if ((unsigned)gz < 64u && (unsigned)gy < 64u && (unsigned)gx < 64u) {
      const int gi = ((b * 64 + gz) * 64 + gy) * 64 + gx;
      v = x[gi] * (float)mask[gi];
    }
    tile[i] = (u16)bfrnd(v);
  }
  __syncthreads();

  const int wv = tid >> 6;
  const int lane = tid & 63;
  const int m = lane & 15;
  const int quad = lane >> 4;
  const int vy = m >> 2, vx = m & 3;

  u32 tof[4][8];
#pragma unroll
  for (int i = 0; i < 4; ++i)
#pragma unroll
    for (int j = 0; j < 8; ++j) tof[i][j] = toff[i * 32 + quad * 8 + j];
  const s16x8* lbv = (const s16x8*)lb;
  s16x8 bfr[4];
#pragma unroll
  for (int i = 0; i < 4; ++i) bfr[i] = lbv[i * 64 + lane];

  for (int s = 0; s < 8; ++s) {
    const int sz = (s >> 2) * 4, sy = ((s >> 1) & 1) * 4, sx = (s & 1) * 4;

    if (tid < 64) {
      const int oz2 = z0 + sz + (tid >> 4);
      const int oy2 = y0 + sy + ((tid >> 2) & 3);
      const int ox2 = x0 + sx + (tid & 3);
      lmsk[tid] = (float)mask[((b * 64 + oz2) * 64 + oy2) * 64 + ox2];
    }

    const int vbase = (sz + wv) * 144 + (sy + vy) * 12 + (sx + vx);
    f32x4 acc = {0.f, 0.f, 0.f, 0.f};
#pragma unroll
    for (int i = 0; i < 4; ++i) {
      s16x8 af;
#pragma unroll
      for (int j = 0; j < 8; ++j)
        af[j] = (short)tile[vbase + tof[i][j]];
      acc = __builtin_amdgcn_mfma_f32_16x16x32_bf16(af, bfr[i], acc, 0, 0, 0);
    }
    __syncthreads();

    {
      float* lCw = lC + wv * 272;
      const int n = lane & 15;
#pragma unroll
      for (int reg = 0; reg < 4; ++reg) {
        const int row = quad * 4 + reg;
        lCw[row * 17 + n] = fmaxf(acc[reg], 0.f) * lmsk[wv * 16 + row];
      }
    }
    __syncthreads();

    {
      const int vox_l = tid >> 2;
      const int cg = (tid & 3) * 4;
      const float* src = lC + (vox_l >> 4) * 272 + (vox_l & 15) * 17 + cg;
      const float f0 = src[0], f1 = src[1], f2 = src[2], f3 = src[3];
      const int Z = z0 + sz + (vox_l >> 4);
      const int Y = y0 + sy + ((vox_l >> 2) & 3);
      const int X = x0 + sx + (vox_l & 3);
      const int gi = ((b * 64 + Z) * 64 + Y) * 64 + X;
      uint2* op = (uint2*)(yout + (size_t)gi * CH + cg);
      op[0] = make_uint2(packbf(f0, f1), packbf(f2, f3));
    }
  }
}

// ---- Stages 0..2: MFMA implicit GEMM, 4 voxel-groups per wave -------------
// Block = 256 voxels (wave = 64 vox = 4 m-groups of 16). Per tap i: 4
// independent A-loads + shared B ds_read + 4 independent MFMAs -> 4x
// load-level parallelism vs 1-chain R10. B prebuilt in global (bpre).
__global__ __launch_bounds__(256) void stage_mfma4(
    const u16* __restrict__ yin, const u16* __restrict__ bpre,
    const int* __restrict__ m_in_i, const float* __restrict__ m_in_f,
    u16* __restrict__ yout, float* __restrict__ m_out,
    float* __restrict__ pool_sum, float* __restrict__ cnt,
    const int S, const int stage)
{
  __shared__ u16 lb[14 * 512];          // 14 KB
  __shared__ float lC[4 * 16 * 17];
  __shared__ float lmp[256];

  const int So = S >> 1;
  const int nvox = So * So * So;
  const int b = blockIdx.y;
  const int tid = threadIdx.x;
  const int vg0 = blockIdx.x * 256;

  // copy prebuilt B fragments -> LDS (coalesced 16B)
  {
    const uint4* src = (const uint4*)bpre;
    uint4* dst = (uint4*)lb;
    for (int e = tid; e < 896; e += 256) dst[e] = src[e];
  }

  // pooled mask: each thread pools its own voxel
  {
    const int vox = vg0 + tid;
    const int oz = vox / (So * So);
    const int oy = (vox / So) % So;
    const int ox = vox % So;
    float mp = 0.f;
#pragma unroll
    for (int dz = 0; dz < 2; ++dz)
#pragma unroll
      for (int dy = 0; dy < 2; ++dy)
#pragma unroll
        for (int dx = 0; dx < 2; ++dx) {
          const int mi =
              ((b * S + 2 * oz + dz) * S + 2 * oy + dy) * S + 2 * ox + dx;
          const float mv = m_in_i ? (float)m_in_i[mi] : m_in_f[mi];
          mp = fmaxf(mp, mv);
        }
    lmp[tid] = mp;
  }
  __syncthreads();

  const int wv = tid >> 6;
  const int lane = tid & 63;
  const int m = lane & 15;
  const int quad = lane >> 4;
  const int qh = quad >> 1;
  const int qlo = quad & 1;

  int izb[4], iyb[4], ixb[4];
#pragma unroll
  for (int g = 0; g < 4; ++g) {
    const int vox = vg0 + wv * 64 + g * 16 + m;
    const int oz = vox / (So * So);
    const int oy = (vox / So) % So;
    const int ox = vox % So;
    izb[g] = 2 * oz - 1;
    iyb[g] = 2 * oy - 1;
    ixb[g] = 2 * ox - 1;
  }

  const s16x8* lbv = (const s16x8*)lb;
  f32x4 acc[4];
#pragma unroll
  for (int g = 0; g < 4; ++g) acc[g] = (f32x4){0.f, 0.f, 0.f, 0.f};

#pragma unroll
  for (int i = 0; i < 14; ++i) {
    const int t0 = 2 * i, t1 = 2 * i + 1;
    const int dz0 = t0 / 9, dy0 = (t0 / 3) % 3, dx0 = t0 % 3;
    const int dz1 = (t1 < 27) ? t1 / 9 : 1;
    const int dy1 = (t1 < 27) ? (t1 / 3) % 3 : 1;
    const int dx1 = (t1 < 27) ? t1 % 3 : 1;
    const int dzq = qh ? dz1 : dz0;
    const int dyq = qh ? dy1 : dy0;
    const int dxq = qh ? dx1 : dx0;

    uint4 ar[4];
#pragma unroll
    for (int g = 0; g < 4; ++g) {
      const int iz = izb[g] + dzq;
      const int iy = iyb[g] + dyq;
      const int ix = ixb[g] + dxq;
      const bool valid = (unsigned)iz < (unsigned)S &&
                         (unsigned)iy < (unsigned)S &&
                         (unsigned)ix < (unsigned)S;
      const int izc = min(max(iz, 0), S - 1);
      const int iyc = min(max(iy, 0), S - 1);
      const int ixc = min(max(ix, 0), S - 1);
      const size_t addr =
          (size_t)(((b * S + izc) * S + iyc) * S + ixc) * 16 + qlo * 8;
      uint4 v = *(const uint4*)(yin + addr);
      v.x = valid ? v.x : 0u;
      v.y = valid ? v.y : 0u;
      v.z = valid ? v.z : 0u;
      v.w = valid ? v.w : 0u;
      ar[g] = v;
    }
    const s16x8 bfrag = lbv[i * 64 + lane];
#pragma unroll
    for (int g = 0; g < 4; ++g)
      acc[g] = __builtin_amdgcn_mfma_f32_16x16x32_bf16(
          __builtin_bit_cast(s16x8, ar[g]), bfrag, acc[g], 0, 0, 0);
  }

  // epilogue: 4 phases through the small lC buffer
  float psum = 0.f;
#pragma unroll
  for (int g = 0; g < 4; ++g) {
    __syncthreads();                    // lC free
    {
      float* lCw = lC + wv * 272;
      const int n = lane & 15;
#pragma unroll
      for (int reg = 0; reg < 4; ++reg) {
        const int row = quad * 4 + reg;
        lCw[row * 17 + n] =
            fmaxf(acc[g][reg], 0.f) * lmp[wv * 64 + g * 16 + row];
      }
    }
    __syncthreads();                    // lC ready
    {
      const int vox_l = tid >> 2;
      const int cg = (tid & 3) * 4;
      const float* src = lC + (vox_l >> 4) * 272 + (vox_l & 15) * 17 + cg;
      const float f0 = src[0], f1 = src[1], f2 = src[2], f3 = src[3];
      const int lv = (vox_l >> 4) * 64 + g * 16 + (vox_l & 15);
      const size_t gi = (size_t)b * nvox + vg0 + lv;
      uint2* op = (uint2*)(yout + gi * 16 + cg);
      op[0] = make_uint2(packbf(f0, f1), packbf(f2, f3));
      if ((tid & 3) == 0) m_out[gi] = lmp[lv];
    }
    if (tid < 16) {
      float s = 0.f;
#pragma unroll 16
      for (int v = 0; v < 64; ++v)
        s += lC[(v >> 4) * 272 + (v & 15) * 17 + tid];
      psum += s;
    }
  }
  if (tid < 16) {
    atomicAdd(&pool_sum[(b * 6 + stage) * 16 + tid], psum);
  } else if (tid == 16) {
    float c = 0.f;
#pragma unroll 16
    for (int v = 0; v < 256; ++v) c += lmp[v];
    atomicAdd(&cnt[b * 6 + stage], c);
  }
}

// --------- Tail: stages 3,4,5 entirely in LDS + pools + full head MLP ------
__global__ __launch_bounds__(256) void tail_kernel(
    const u16* __restrict__ y3g, const float* __restrict__ m3g,
    const float* __restrict__ wstg,
    const float* __restrict__ meta, const float* __restrict__ sched,
    const float* __restrict__ mw1, const float* __restrict__ mb1,
    const float* __restrict__ mw2, const float* __restrict__ mb2,
    const float* __restrict__ matw, const float* __restrict__ matb,
    const float* __restrict__ schw, const float* __restrict__ schb,
    const float* __restrict__ f1w, const float* __restrict__ f1b,
    const float* __restrict__ f2w, const float* __restrict__ f2b,
    const float* __restrict__ pool_sum, const float* __restrict__ cnt,
    float* __restrict__ out)
{
  const int b = blockIdx.x;
  const int t = threadIdx.x;
  __shared__ float ly3[8 * 8 * 8 * 16];
  __shared__ float lm3[512];
  __shared__ float ly4[4 * 4 * 4 * 16];
  __shared__ float lm4[64];
  __shared__ float ly5[8 * 16];
  __shared__ float lm5[8];
  __shared__ float lsum[3][16];
  __shared__ float lcnt[3];
  __shared__ float invec[112];
  __shared__ float hbuf[32];
  __shared__ float zbuf[256];
  __shared__ float part[2];

  const uint4* yb = (const uint4*)(y3g + (size_t)b * 8192);
  for (int i = t; i < 1024; i += 256) {
    const uint4 p = yb[i];
    float* d = &ly3[i * 8];
    d[0] = bflo(p.x); d[1] = bfhi(p.x);
    d[2] = bflo(p.y); d[3] = bfhi(p.y);
    d[4] = bflo(p.z); d[5] = bfhi(p.z);
    d[6] = bflo(p.w); d[7] = bfhi(p.w);
  }
  for (int i = t; i < 512; i += 256) lm3[i] = m3g[b * 512 + i];
  __syncthreads();

  // ---- stage 3: 8^3 -> 4^3, thread = (vox, co-group of 4)
  {
    const float* w = wstg + 3 * 27 * 256;
    const int vox = t >> 2, cog = (t & 3) * 4;
    const int oz = vox >> 4, oy = (vox >> 2) & 3, ox = vox & 3;
    float acc[4] = {0.f, 0.f, 0.f, 0.f};
#pragma unroll
    for (int dz = 0; dz < 3; ++dz)
#pragma unroll
      for (int dy = 0; dy < 3; ++dy)
#pragma unroll
        for (int dx = 0; dx < 3; ++dx) {
          const int iz = 2 * oz + dz - 1, iy = 2 * oy + dy - 1,
                    ix = 2 * ox + dx - 1;
          const float s = ((unsigned)iz < 8u && (unsigned)iy < 8u &&
                           (unsigned)ix < 8u) ? 1.f : 0.f;
          const int idx = ((min(max(iz, 0), 7) * 8 + min(max(iy, 0), 7)) * 8 +
                           min(max(ix, 0), 7)) * 16;
          const float* wp = w + ((dz * 3 + dy) * 3 + dx) * 256;
#pragma unroll
          for (int ci = 0; ci < 16; ++ci) {
            const float v = ly3[idx + ci] * s;
#pragma unroll
            for (int c = 0; c < 4; ++c)
              acc[c] = fmaf(v, wp[ci * 16 + cog + c], acc[c]);
          }
        }
    float mp = 0.f;
#pragma unroll
    for (int dz = 0; dz < 2; ++dz)
#pragma unroll
      for (int dy = 0; dy < 2; ++dy)
#pragma unroll
        for (int dx = 0; dx < 2; ++dx)
          mp = fmaxf(mp, lm3[((2 * oz + dz) * 8 + 2 * oy + dy) * 8 +
                             2 * ox + dx]);
#pragma unroll
    for (int c = 0; c < 4; ++c)
      ly4[vox * 16 + cog + c] = fmaxf(acc[c], 0.f) * mp;
    if (cog == 0) lm4[vox] = mp;
  }
  __syncthreads();

  // ---- stage-3 sums and stage 4: 4^3 -> 2^3
  if (t < 16) {
    float s = 0.f;
#pragma unroll 16
    for (int v = 0; v < 64; ++v) s += ly4[v * 16 + t];
    lsum[0][t] = s;
  } else if (t == 16) {
    float s = 0.f;
#pragma unroll 16
    for (int v = 0; v < 64; ++v) s += lm4[v];
    lcnt[0] = s;
  }
  float s4val = 0.f, s4mp = 0.f;
  const int vox4 = (t >> 4) & 7, co4 = t & 15;
  if (t < 128) {
    const float* w = wstg + 4 * 27 * 256;
    const int oz = vox4 >> 2, oy = (vox4 >> 1) & 1, ox = vox4 & 1;
    float acc = 0.f;
#pragma unroll
    for (int dz = 0; dz < 3; ++dz)
#pragma unroll
      for (int dy = 0; dy < 3; ++dy)
#pragma unroll
        for (int dx = 0; dx < 3; ++dx) {
          const int iz = 2 * oz + dz - 1, iy = 2 * oy + dy - 1,
                    ix = 2 * ox + dx - 1;
          const float s = ((unsigned)iz < 4u && (unsigned)iy < 4u &&
                           (unsigned)ix < 4u) ? 1.f : 0.f;
          const int idx = ((min(max(iz, 0), 3) * 4 + min(max(iy, 0), 3)) * 4 +
                           min(max(ix, 0), 3)) * 16;
          const float* wp = w + ((dz * 3 + dy) * 3 + dx) * 256 + co4;
#pragma unroll
          for (int ci = 0; ci < 16; ++ci)
            acc = fmaf(ly4[idx + ci] * s, wp[ci * 16], acc);
        }
    float mp = 0.f;
#pragma unroll
    for (int dz = 0; dz < 2; ++dz)
#pragma unroll
      for (int dy = 0; dy < 2; ++dy)
#pragma unroll
        for (int dx = 0; dx < 2; ++dx)
          mp = fmaxf(mp, lm4[((2 * (vox4 >> 2) + dz) * 4 +
                              2 * ((vox4 >> 1) & 1) + dy) * 4 +
                             2 * (vox4 & 1) + dx]);
    s4val = fmaxf(acc, 0.f) * mp;
    s4mp = mp;
  }
  __syncthreads();
  if (t < 128) {
    ly5[vox4 * 16 + co4] = s4val;
    if (co4 == 0) lm5[vox4] = s4mp;
  }
  __syncthreads();

  // ---- stage-4 sums and stage 5: 2^3 -> 1
  if (t < 16) {
    float s = 0.f;
#pragma unroll
    for (int v = 0; v < 8; ++v) s += ly5[v * 16 + t];
    lsum[1][t] = s;
  } else if (t == 16) {
    lcnt[1] = lm5[0] + lm5[1] + lm5[2] + lm5[3] + lm5[4] + lm5[5] + lm5[6] +
              lm5[7];
  }
  if (t >= 64 && t < 80) {
    const int co = t - 64;
    const float* w = wstg + 5 * 27 * 256;
    float acc = 0.f;
#pragma unroll
    for (int dz = 0; dz < 3; ++dz)
#pragma unroll
      for (int dy = 0; dy < 3; ++dy)
#pragma unroll
        for (int dx = 0; dx < 3; ++dx) {
          const int iz = dz - 1, iy = dy - 1, ix = dx - 1;
          const float s = ((unsigned)iz < 2u && (unsigned)iy < 2u &&
                           (unsigned)ix < 2u) ? 1.f : 0.f;
          const int idx = ((min(max(iz, 0), 1) * 2 + min(max(iy, 0), 1)) * 2 +
                           min(max(ix, 0), 1)) * 16;
          const float* wp = w + ((dz * 3 + dy) * 3 + dx) * 256 + co;
#pragma unroll
          for (int ci = 0; ci < 16; ++ci)
            acc = fmaf(ly5[idx + ci] * s, wp[ci * 16], acc);
        }
    float mp = 0.f;
#pragma unroll
    for (int v = 0; v < 8; ++v) mp = fmaxf(mp, lm5[v]);
    lsum[2][co] = fmaxf(acc, 0.f) * mp;
    if (co == 0) lcnt[2] = mp;
  }
  __syncthreads();

  // ---- build invec; meta layer 1
  if (t < 48) {
    const int s = t >> 4;
    invec[t] = pool_sum[b * 96 + t] / fmaxf(cnt[b * 6 + s], 1.f);
  } else if (t < 96) {
    const int s = (t >> 4) - 3;
    invec[t] = lsum[s][t & 15] / fmaxf(lcnt[s], 1.f);
  } else if (t < 128) {
    const int j = t - 96;
    float h = mb1[j];
#pragma unroll
    for (int k = 0; k < 3; ++k) h = fmaf(meta[b * 3 + k], mw1[k * 32 + j], h);
    hbuf[j] = fmaxf(h, 0.f);
  }
  __syncthreads();
  if (t < 16) {
    float e = mb2[t];
#pragma unroll
    for (int j = 0; j < 32; ++j) e = fmaf(hbuf[j], mw2[j * 16 + t], e);
    invec[96 + t] = e;  // no ReLU on meta_emb
  }
  __syncthreads();
  if (t < 128) {
    float a = matb[t];
#pragma unroll 16
    for (int k = 0; k < 112; ++k) a = fmaf(invec[k], matw[k * 128 + t], a);
    zbuf[t] = fmaxf(a, 0.f);
    float s = schb[t];
#pragma unroll 16
    for (int k = 0; k < 128; ++k)
      s = fmaf(sched[b * 128 + k], schw[k * 128 + t], s);
    zbuf[128 + t] = fmaxf(s, 0.f);
  }
  __syncthreads();
  if (t < 128) {
    float a = f1b[t];
#pragma unroll 16
    for (int k = 0; k < 256; ++k) a = fmaf(zbuf[k], f1w[k * 128 + t], a);
    float v = fmaxf(a, 0.f) * f2w[t];
#pragma unroll
    for (int off = 32; off > 0; off >>= 1) v += __shfl_xor(v, off, 64);
    if ((t & 63) == 0) part[t >> 6] = v;
  }
  __syncthreads();
  if (t == 0) out[b] = part[0] + part[1] + f2b[0];
}

extern "C" void kernel_launch(void* const* d_in, const int* in_sizes, int n_in,
                              void* d_out, int out_size, void* d_ws,
                              size_t ws_size, hipStream_t stream)
{
  (void)in_sizes; (void)n_in; (void)out_size; (void)ws_size;
  const float* x      = (const float*)d_in[0];
  const int*   mask   = (const int*)  d_in[1];
  const float* meta   = (const float*)d_in[2];
  const float* sched  = (const float*)d_in[3];
  const float* w_stem = (const float*)d_in[4];
  const float* w_stg  = (const float*)d_in[5];
  const float* mw1    = (const float*)d_in[6];
  const float* mb1    = (const float*)d_in[7];
  const float* mw2    = (const float*)d_in[8];
  const float* mb2    = (const float*)d_in[9];
  const float* matw   = (const float*)d_in[10];
  const float* matb   = (const float*)d_in[11];
  const float* schw   = (const float*)d_in[12];
  const float* schb   = (const float*)d_in[13];
  const float* f1w    = (const float*)d_in[14];
  const float* f1b    = (const float*)d_in[15];
  const float* f2w    = (const float*)d_in[16];
  const float* f2b    = (const float*)d_in[17];
  float* out = (float*)d_out;

  char* ws = (char*)d_ws;
  size_t off = 0;
  auto alloc = [&](size_t nbytes) -> void* {
    void* p = ws + off;
    off += (nbytes + 255) & ~(size_t)255;
    return p;
  };

  u16* y0 = (u16*)alloc((size_t)NB * 64 * 64 * 64 * CH * 2);
  u16* y1 = (u16*)alloc((size_t)NB * 32 * 32 * 32 * CH * 2);
  u16* y2 = (u16*)alloc((size_t)NB * 16 * 16 * 16 * CH * 2);
  u16* y3 = (u16*)alloc((size_t)NB * 8 * 8 * 8 * CH * 2);
  float* m1 = (float*)alloc((size_t)NB * 32 * 32 * 32 * 4);
  float* m2 = (float*)alloc((size_t)NB * 16 * 16 * 16 * 4);
  float* m3 = (float*)alloc((size_t)NB * 8 * 8 * 8 * 4);
  float* pool_sum = (float*)alloc((NB * 96 + NB * 6) * 4);
  float* cnt = pool_sum + NB * 96;
  u16* bpre = (u16*)alloc(3 * 7168 * 2);

  bprep_kernel<<<84, 256, 0, stream>>>(w_stg, bpre);

  stem_mfma<<<dim3(512, NB), 256, 0, stream>>>(x, mask, w_stem, y0,
                                               pool_sum, cnt);

  // stage 0: 64->32 (32768 vox / 256 = 128 blocks/batch)
  stage_mfma4<<<dim3(128, NB), 256, 0, stream>>>(
      y0, bpre + 0 * 7168, mask, (const float*)nullptr, y1, m1,
      pool_sum, cnt, 64, 0);
  // stage 1: 32->16 (16 blocks/batch)
  stage_mfma4<<<dim3(16, NB), 256, 0, stream>>>(
      y1, bpre + 1 * 7168, (const int*)nullptr, m1, y2, m2,
      pool_sum, cnt, 32, 1);
  // stage 2: 16->8 (2 blocks/batch)
  stage_mfma4<<<dim3(2, NB), 256, 0, stream>>>(
      y2, bpre + 2 * 7168, (const int*)nullptr, m2, y3, m3,
      pool_sum, cnt, 16, 2);

  tail_kernel<<<NB, 256, 0, stream>>>(y3, m3, w_stg, meta, sched,
                                      mw1, mb1, mw2, mb2, matw, matb,
                                      schw, schb, f1w, f1b, f2w, f2b,
                                      pool_sum, cnt, out);
}